// Round 5
// baseline (694.168 us; speedup 1.0000x reference)
//
#include <hip/hip_runtime.h>
#include <cstdint>

#define D_MODEL 768
#define NHEAD 12
#define HDIM 64
#define LSEQ 257
#define NBATCH 64
#define MROWS (LSEQ*NBATCH)   // 16448

typedef unsigned short u16;
typedef __attribute__((ext_vector_type(8))) short short8;
typedef __attribute__((ext_vector_type(4))) float floatx4;

__device__ __forceinline__ float b2f(u16 u){ return __uint_as_float(((unsigned)u)<<16); }
__device__ __forceinline__ u16 f2bf(float f){
  unsigned x = __float_as_uint(f);
  return (u16)((x + 0x7fffu + ((x>>16)&1u)) >> 16);
}

// async global->LDS, 16B per lane; LDS dest is wave-uniform base (HW adds lane*16);
// global source address is per-lane.
__device__ __forceinline__ void async16(const u16* g, u16* l) {
  __builtin_amdgcn_global_load_lds(
      (const __attribute__((address_space(1))) unsigned int*)g,
      (__attribute__((address_space(3))) unsigned int*)l, 16, 0, 0);
}

// ---------------- fp32 -> bf16 weight conversion (done once per launch) ----------------
__global__ __launch_bounds__(256) void cvt_bf16(const float* __restrict__ in,
                                                u16* __restrict__ out, int n8)
{
  int i = blockIdx.x*256 + threadIdx.x;
  if (i >= n8) return;
  const float4* p = (const float4*)in + (size_t)i*2;
  float4 a = p[0], b = p[1];
  u16 t[8] = {f2bf(a.x),f2bf(a.y),f2bf(a.z),f2bf(a.w),
              f2bf(b.x),f2bf(b.y),f2bf(b.z),f2bf(b.w)};
  *(uint4*)(out + (size_t)i*8) = *(const uint4*)t;
}

// ---------------- LayerNorm: one wave per row of 768 ----------------
template<typename TIN>
__global__ __launch_bounds__(256) void ln_kernel(const TIN* __restrict__ x,
    const float* __restrict__ g, const float* __restrict__ b,
    u16* __restrict__ out, int rows)
{
  int wv = threadIdx.x >> 6, lane = threadIdx.x & 63;
  int row = blockIdx.x*4 + wv;
  if (row >= rows) return;
  const TIN* xr = x + (size_t)row*D_MODEL;
  float v[12]; float s = 0.f, s2 = 0.f;
#pragma unroll
  for (int i=0;i<12;++i){
    float f;
    if constexpr (sizeof(TIN)==2) f = b2f(((const u16*)xr)[lane + i*64]);
    else                          f = ((const float*)xr)[lane + i*64];
    v[i]=f; s+=f; s2+=f*f;
  }
#pragma unroll
  for (int o=32;o>0;o>>=1){ s += __shfl_xor(s,o,64); s2 += __shfl_xor(s2,o,64); }
  float mu = s*(1.f/768.f);
  float var = fmaxf(s2*(1.f/768.f) - mu*mu, 0.f);
  float rs = rsqrtf(var + 1e-5f);
  u16* orow = out + (size_t)row*D_MODEL;
#pragma unroll
  for (int i=0;i<12;++i){
    int c = lane + i*64;
    orow[c] = f2bf((v[i]-mu)*rs*g[c] + b[c]);
  }
}

// ---------------- GEMM: C[M,N] = A[M,K](bf16) * B[N,K]^T(bf16) + bias ----------------
// EPI 0: C=bf16(acc+bias)
// EPI 1: C=bf16(resid_f32 + acc+bias)
// EPI 2: y=acc+bias; C=f32(resid_bf16 + y*sigmoid(1.702y))
// BK=64, both-sides XOR swizzle (round-4, verified), now DOUBLE-BUFFERED with raw
// s_barrier + counted vmcnt(8): next tile's 8 global_load_lds stay in flight across
// the barrier and complete under the MFMA phase (T3 minimum-2-phase recipe).
#define BM 128
#define BN 128
#define BK 64

template<int EPI>
__global__ __launch_bounds__(256,2) void gemm_bt(
    const u16* __restrict__ A, const u16* __restrict__ B,
    const float* __restrict__ bias, void* __restrict__ Cout,
    const void* __restrict__ resid, int M, int N, int K)
{
  __shared__ u16 sA[2][BM*BK];   // 2 x 16 KB
  __shared__ u16 sB[2][BN*BK];   // 2 x 16 KB
  const int m0 = blockIdx.y * BM, n0 = blockIdx.x * BN;   // x = N-dim so consecutive blocks share A-tile
  const int tid = threadIdx.x;
  const int lane = tid & 63, w = tid >> 6;
  const int wm = (w>>1)*64, wn = (w&1)*64;
  const int l16 = lane & 15, quad = lane >> 4;
  // staging: wave w owns rows [w*32, w*32+32), 4 chunks x 8 rows; lane -> row l>>3, slot l&7.
  const int srow = lane >> 3;
  const int scol = ((lane & 7) ^ srow) * 8;   // inverse-swizzled source col chunk
  const u16* gA[4]; const u16* gB[4];
#pragma unroll
  for (int c=0;c<4;++c) {
    int ra = m0 + w*32 + c*8 + srow; if (ra >= M) ra = M-1;  // clamp tail: stay in-buffer
    gA[c] = A + (size_t)ra*K + scol;
    int rb = n0 + w*32 + c*8 + srow;                          // N is always a multiple of 128
    gB[c] = B + (size_t)rb*K + scol;
  }
  const int lw = w*32*BK;

  floatx4 acc[4][4];
#pragma unroll
  for (int i=0;i<4;++i)
#pragma unroll
    for (int j=0;j<4;++j) acc[i][j] = (floatx4){0.f,0.f,0.f,0.f};

  const int nt = K >> 6;   // K/BK (=12 for K=768)
  // prologue: stage tile 0 into buf 0
#pragma unroll
  for (int c=0;c<4;++c) async16(gA[c], &sA[0][lw + c*8*BK]);
#pragma unroll
  for (int c=0;c<4;++c) async16(gB[c], &sB[0][lw + c*8*BK]);

  for (int t=0; t<nt; ++t) {
    const int cur = t & 1;
    if (t+1 < nt) {
      const int k1 = (t+1)*BK;
#pragma unroll
      for (int c=0;c<4;++c) async16(gA[c] + k1, &sA[1-cur][lw + c*8*BK]);
#pragma unroll
      for (int c=0;c<4;++c) async16(gB[c] + k1, &sB[1-cur][lw + c*8*BK]);
      // wait only for the oldest 8 (current buffer); prefetch stays in flight
      asm volatile("s_waitcnt vmcnt(8)" ::: "memory");
    } else {
      asm volatile("s_waitcnt vmcnt(0)" ::: "memory");
    }
    __builtin_amdgcn_s_barrier();          // all waves' current-buffer loads landed
    __builtin_amdgcn_sched_barrier(0);     // no hoisting of ds_reads above the wait
#pragma unroll
    for (int ks=0;ks<2;++ks) {
      short8 af[4], bfr[4];
#pragma unroll
      for (int tt=0;tt<4;++tt)
        af[tt]  = *(const short8*)(&sA[cur][(wm + tt*16 + l16)*BK + ((ks*4+quad) ^ (l16&7))*8]);
#pragma unroll
      for (int tt=0;tt<4;++tt)
        bfr[tt] = *(const short8*)(&sB[cur][(wn + tt*16 + l16)*BK + ((ks*4+quad) ^ (l16&7))*8]);
#pragma unroll
      for (int mt=0;mt<4;++mt)
#pragma unroll
        for (int ntt=0;ntt<4;++ntt)
          acc[mt][ntt] = __builtin_amdgcn_mfma_f32_16x16x32_bf16(af[mt], bfr[ntt], acc[mt][ntt], 0,0,0);
    }
    __builtin_amdgcn_sched_barrier(0);
    __builtin_amdgcn_s_barrier();          // all waves done reading buf[cur] (reads drained pre-MFMA)
  }

#pragma unroll
  for (int mt=0;mt<4;++mt)
#pragma unroll
    for (int ntc=0;ntc<4;++ntc) {
      int col = n0 + wn + ntc*16 + l16;
      if (col >= N) continue;
      float bia = bias[col];
      int rowb = m0 + wm + mt*16 + quad*4;
#pragma unroll
      for (int r=0;r<4;++r) {
        int row = rowb + r;
        if (row >= M) continue;
        float vacc = acc[mt][ntc][r] + bia;
        size_t off = (size_t)row*N + col;
        if (EPI==0) {
          ((u16*)Cout)[off] = f2bf(vacc);
        } else if (EPI==1) {
          ((u16*)Cout)[off] = f2bf(((const float*)resid)[off] + vacc);
        } else {
          float gl = vacc / (1.f + __expf(-1.702f*vacc));
          ((float*)Cout)[off] = b2f(((const u16*)resid)[off]) + gl;
        }
      }
    }
}

// ---------------- Fused attention: per (n,h) pair x 64-row Q tile (round-2 measured version) ----------------
__global__ __launch_bounds__(256,2) void attn_kernel(
    const u16* __restrict__ qkv, float* __restrict__ wout, u16* __restrict__ attn)
{
  __shared__ __align__(16) u16 smem[29696];  // 59392 B
  u16* sQ  = smem;               // [64][72]
  u16* sK  = smem + 64*72;       // [272][72]
  u16* sP  = smem;               // [64][296]
  u16* sVt = smem + 64*296;      // [64][168]
  const int p = blockIdx.x;      // n*12 + h
  const int n = p / NHEAD, h = p % NHEAD;
  const int l0 = blockIdx.y * 64;
  const int tid = threadIdx.x, lane = tid & 63, w = tid >> 6;
  const int l16 = lane & 15, quad = lane >> 4;

  for (int i = tid; i < 64*8; i += 256) {
    int lr = i >> 3, c8 = (i & 7)*8;
    uint4 v = {0u,0u,0u,0u};
    int gl = l0 + lr;
    if (gl < LSEQ) v = *(const uint4*)(qkv + ((size_t)gl*NBATCH + n)*2304 + h*HDIM + c8);
    *(uint4*)(sQ + lr*72 + c8) = v;
  }
  for (int i = tid; i < 272*8; i += 256) {
    int kr = i >> 3, c8 = (i & 7)*8;
    uint4 v = {0u,0u,0u,0u};
    if (kr < LSEQ) v = *(const uint4*)(qkv + ((size_t)kr*NBATCH + n)*2304 + 768 + h*HDIM + c8);
    *(uint4*)(sK + kr*72 + c8) = v;
  }
  __syncthreads();

  floatx4 acc[17];
#pragma unroll
  for (int t=0;t<17;++t) acc[t] = (floatx4){0.f,0.f,0.f,0.f};
#pragma unroll
  for (int ks=0;ks<2;++ks) {
    short8 aq = *(const short8*)(sQ + (w*16 + l16)*72 + ks*32 + quad*8);
#pragma unroll
    for (int nt=0;nt<17;++nt) {
      short8 bk = *(const short8*)(sK + (nt*16 + l16)*72 + ks*32 + quad*8);
      acc[nt] = __builtin_amdgcn_mfma_f32_16x16x32_bf16(aq, bk, acc[nt], 0,0,0);
    }
  }
  __syncthreads();  // all sQ/sK reads complete before sP overwrites

#pragma unroll
  for (int r=0;r<4;++r) {
    float mx = -3.0e38f;
#pragma unroll
    for (int nt=0;nt<17;++nt) {
      int col = nt*16 + l16;
      float v = (col < LSEQ) ? acc[nt][r]*0.125f : -3.0e38f;
      acc[nt][r] = v;
      mx = fmaxf(mx, v);
    }
#pragma unroll
    for (int o=1;o<16;o<<=1) mx = fmaxf(mx, __shfl_xor(mx,o,64));
    float sum = 0.f;
#pragma unroll
    for (int nt=0;nt<17;++nt) {
      float e = __expf(acc[nt][r]-mx);
      acc[nt][r] = e; sum += e;
    }
#pragma unroll
    for (int o=1;o<16;o<<=1) sum += __shfl_xor(sum,o,64);
    float inv = 1.f/sum;
#pragma unroll
    for (int nt=0;nt<17;++nt) acc[nt][r] *= inv;
  }

  size_t wbase = (size_t)p * LSEQ * LSEQ;
#pragma unroll
  for (int r=0;r<4;++r) {
    int lr = w*16 + quad*4 + r;
    int gl = l0 + lr;
#pragma unroll
    for (int nt=0;nt<17;++nt) {
      int col = nt*16 + l16;
      sP[lr*296 + col] = f2bf(acc[nt][r]);
      if (gl < LSEQ && col < LSEQ) wout[wbase + (size_t)gl*LSEQ + col] = acc[nt][r];
    }
  }
  for (int i = tid; i < 64*16; i += 256) {
    int lr = i >> 4, c = 272 + (i & 15);
    sP[lr*296 + c] = 0;
  }
  __syncthreads();

  floatx4 acc2[4];
#pragma unroll
  for (int t=0;t<4;++t) acc2[t] = (floatx4){0.f,0.f,0.f,0.f};
  for (int c=0;c<2;++c) {
    if (c) __syncthreads();
    int mbase = c*160;
    int msz = c ? 128 : 160;
    for (int ml = tid; ml < msz; ml += 256) {
      int m = mbase + ml;
      if (m < LSEQ) {
        const u16* vr = qkv + ((size_t)m*NBATCH + n)*2304 + 1536 + h*HDIM;
#pragma unroll
        for (int d=0; d<64; ++d) sVt[d*168 + ml] = vr[d];
      } else {
#pragma unroll
        for (int d=0; d<64; ++d) sVt[d*168 + ml] = 0;
      }
    }
    __syncthreads();
    int nks = c ? 4 : 5;
    for (int ksl=0; ksl<nks; ++ksl) {
      short8 ap = *(const short8*)(sP + (w*16 + l16)*296 + mbase + ksl*32 + quad*8);
#pragma unroll
      for (int nt=0;nt<4;++nt) {
        short8 bv = *(const short8*)(sVt + (nt*16 + l16)*168 + ksl*32 + quad*8);
        acc2[nt] = __builtin_amdgcn_mfma_f32_16x16x32_bf16(ap, bv, acc2[nt], 0,0,0);
      }
    }
  }
#pragma unroll
  for (int nt=0;nt<4;++nt)
#pragma unroll
    for (int r=0;r<4;++r) {
      int lr = w*16 + quad*4 + r;
      int gl = l0 + lr;
      if (gl < LSEQ) {
        int d = nt*16 + l16;
        attn[((size_t)gl*NBATCH + n)*768 + h*HDIM + d] = f2bf(acc2[nt][r]);
      }
    }
}

extern "C" void kernel_launch(void* const* d_in, const int* in_sizes, int n_in,
                              void* d_out, int out_size, void* d_ws, size_t ws_size,
                              hipStream_t stream)
{
  (void)in_sizes; (void)n_in; (void)out_size; (void)ws_size;
  const float* x    = (const float*)d_in[0];
  const float* w_in = (const float*)d_in[1];
  const float* b_in = (const float*)d_in[2];
  const float* w_op = (const float*)d_in[3];
  const float* b_op = (const float*)d_in[4];
  const float* g1   = (const float*)d_in[5];
  const float* b1   = (const float*)d_in[6];
  const float* g2   = (const float*)d_in[7];
  const float* b2v  = (const float*)d_in[8];
  const float* wfc  = (const float*)d_in[9];
  const float* bfc  = (const float*)d_in[10];

  float* out_x = (float*)d_out;
  float* out_w = out_x + (size_t)MROWS*D_MODEL;

  char* ws = (char*)d_ws;
  u16* qkv  = (u16*)ws;                                                 // 75.79 MB
  u16* hbuf = (u16*)(ws + (size_t)MROWS*2304*2);                        // h then attn, 25.26 MB
  u16* x2b  = (u16*)(ws + (size_t)MROWS*2304*2 + (size_t)MROWS*768*2);  // x2 bf16, 25.26 MB

  // Overlaid bf16 weight buffers (no extra workspace):
  //  - w_in_bf in x2b region (x2b first written at out_proj, after QKV GEMM consumed w_in_bf)
  //  - w_op_bf/w_fc_bf at qkv+48MB (qkv dead after attn; LN2 writes only first 25.26MB)
  u16* w_in_bf = x2b;
  u16* w_op_bf = qkv + (size_t)24*1024*1024;
  u16* w_fc_bf = w_op_bf + 768*768;

  dim3 blk(256);
  // convert in_proj weights fp32->bf16 (2304*768/8 = 221184 vec8)
  cvt_bf16<<<dim3(864), blk, 0, stream>>>(w_in, w_in_bf, 221184);
  // LN1: x (fp32) -> h (bf16)
  ln_kernel<float><<<dim3(MROWS/4), blk, 0, stream>>>(x, g1, b1, hbuf, MROWS);
  // QKV: h @ in_proj_w^T + b   (grid: x=N-blocks for A-tile reuse)
  gemm_bt<0><<<dim3(18,129), blk, 0, stream>>>(hbuf, w_in_bf, b_in, qkv, nullptr, MROWS, 2304, 768);
  // attention: qkv -> weights (d_out tail, fp32) + attn (hbuf, bf16)
  attn_kernel<<<dim3(768,5), blk, 0, stream>>>(qkv, out_w, hbuf);
  // convert out_proj / fc weights (qkv now dead)
  cvt_bf16<<<dim3(288), blk, 0, stream>>>(w_op, w_op_bf, 73728);
  cvt_bf16<<<dim3(288), blk, 0, stream>>>(wfc,  w_fc_bf, 73728);
  // out_proj + residual(x fp32) -> x2 (bf16)
  gemm_bt<1><<<dim3(6,129), blk, 0, stream>>>(hbuf, w_op_bf, b_op, x2b, x, MROWS, 768, 768);
  // LN2: x2 (bf16) -> h2 (bf16, reuse qkv buffer head)
  ln_kernel<u16><<<dim3(MROWS/4), blk, 0, stream>>>(x2b, g2, b2v, qkv, MROWS);
  // fc + quickgelu + residual(x2 bf16) -> out_x (fp32)
  gemm_bt<2><<<dim3(6,129), blk, 0, stream>>>(qkv, w_fc_bf, bfc, out_x, x2b, MROWS, 768, 768);
}

// Round 7
// 605.879 us; speedup vs baseline: 1.1457x; 1.1457x over previous
//
#include <hip/hip_runtime.h>
#include <cstdint>

#define D_MODEL 768
#define NHEAD 12
#define HDIM 64
#define LSEQ 257
#define NBATCH 64
#define MROWS (LSEQ*NBATCH)   // 16448

typedef unsigned short u16;
typedef __attribute__((ext_vector_type(8))) short short8;
typedef __attribute__((ext_vector_type(4))) float floatx4;

__device__ __forceinline__ float b2f(u16 u){ return __uint_as_float(((unsigned)u)<<16); }
__device__ __forceinline__ u16 f2bf(float f){
  unsigned x = __float_as_uint(f);
  return (u16)((x + 0x7fffu + ((x>>16)&1u)) >> 16);
}

// async global->LDS, 16B per lane; LDS dest is wave-uniform base (HW adds lane*16);
// global source address is per-lane.
__device__ __forceinline__ void async16(const u16* g, u16* l) {
  __builtin_amdgcn_global_load_lds(
      (const __attribute__((address_space(1))) unsigned int*)g,
      (__attribute__((address_space(3))) unsigned int*)l, 16, 0, 0);
}

// ---------------- fp32 -> bf16 weight conversion (done once per launch) ----------------
__global__ __launch_bounds__(256) void cvt_bf16(const float* __restrict__ in,
                                                u16* __restrict__ out, int n8)
{
  int i = blockIdx.x*256 + threadIdx.x;
  if (i >= n8) return;
  const float4* p = (const float4*)in + (size_t)i*2;
  float4 a = p[0], b = p[1];
  u16 t[8] = {f2bf(a.x),f2bf(a.y),f2bf(a.z),f2bf(a.w),
              f2bf(b.x),f2bf(b.y),f2bf(b.z),f2bf(b.w)};
  *(uint4*)(out + (size_t)i*8) = *(const uint4*)t;
}

// ---------------- LayerNorm: one wave per row of 768 ----------------
template<typename TIN>
__global__ __launch_bounds__(256) void ln_kernel(const TIN* __restrict__ x,
    const float* __restrict__ g, const float* __restrict__ b,
    u16* __restrict__ out, int rows)
{
  int wv = threadIdx.x >> 6, lane = threadIdx.x & 63;
  int row = blockIdx.x*4 + wv;
  if (row >= rows) return;
  const TIN* xr = x + (size_t)row*D_MODEL;
  float v[12]; float s = 0.f, s2 = 0.f;
#pragma unroll
  for (int i=0;i<12;++i){
    float f;
    if constexpr (sizeof(TIN)==2) f = b2f(((const u16*)xr)[lane + i*64]);
    else                          f = ((const float*)xr)[lane + i*64];
    v[i]=f; s+=f; s2+=f*f;
  }
#pragma unroll
  for (int o=32;o>0;o>>=1){ s += __shfl_xor(s,o,64); s2 += __shfl_xor(s2,o,64); }
  float mu = s*(1.f/768.f);
  float var = fmaxf(s2*(1.f/768.f) - mu*mu, 0.f);
  float rs = rsqrtf(var + 1e-5f);
  u16* orow = out + (size_t)row*D_MODEL;
#pragma unroll
  for (int i=0;i<12;++i){
    int c = lane + i*64;
    orow[c] = f2bf((v[i]-mu)*rs*g[c] + b[c]);
  }
}

// ---------------- GEMM: C[M,N] = A[M,K](bf16) * B[N,K]^T(bf16) + bias ----------------
// (round-4 verified version, 611 us total; 32KB LDS -> 5 blocks/CU at VGPR=56.
//  Round-5 post-mortem: dbuf+vmcnt(8) doubled LDS, halved occupancy, +83 us. Occupancy wins here.)
// EPI 0: C=bf16(acc+bias)
// EPI 1: C=bf16(resid_f32 + acc+bias)
// EPI 2: y=acc+bias; C=f32(resid_bf16 + y*sigmoid(1.702y))
// BK=64: halves barrier-drain count vs BK=32, 8 async16/step.
// LDS XOR-swizzle both-sides (rule 21): linear global_load_lds dest; per-lane GLOBAL source
// col pre-swizzled ((l&7)^(l>>3))*8; ds_read uses slot (ks*4+quad)^(l16&7).
#define BM 128
#define BN 128
#define BK 64

template<int EPI>
__global__ __launch_bounds__(256,2) void gemm_bt(
    const u16* __restrict__ A, const u16* __restrict__ B,
    const float* __restrict__ bias, void* __restrict__ Cout,
    const void* __restrict__ resid, int M, int N, int K)
{
  __shared__ u16 sA[BM*BK];   // 16 KB, [128 rows][64 cols] (cols chunk-swizzled)
  __shared__ u16 sB[BN*BK];   // 16 KB
  const int m0 = blockIdx.y * BM, n0 = blockIdx.x * BN;   // x = N-dim so consecutive blocks share A-tile
  const int tid = threadIdx.x;
  const int lane = tid & 63, w = tid >> 6;
  const int wm = (w>>1)*64, wn = (w&1)*64;
  const int l16 = lane & 15, quad = lane >> 4;
  // staging: wave w owns rows [w*32, w*32+32), 4 chunks x 8 rows; lane -> row l>>3, slot l&7.
  const int srow = lane >> 3;
  const int scol = ((lane & 7) ^ srow) * 8;   // inverse-swizzled source col chunk
  const u16* gA[4]; const u16* gB[4];
#pragma unroll
  for (int c=0;c<4;++c) {
    int ra = m0 + w*32 + c*8 + srow; if (ra >= M) ra = M-1;  // clamp tail: stay in-buffer
    gA[c] = A + (size_t)ra*K + scol;
    int rb = n0 + w*32 + c*8 + srow;                          // N is always a multiple of 128
    gB[c] = B + (size_t)rb*K + scol;
  }
  u16* lA0 = sA + w*32*BK;
  u16* lB0 = sB + w*32*BK;

  floatx4 acc[4][4];
#pragma unroll
  for (int i=0;i<4;++i)
#pragma unroll
    for (int j=0;j<4;++j) acc[i][j] = (floatx4){0.f,0.f,0.f,0.f};

  for (int k0=0;k0<K;k0+=BK) {
#pragma unroll
    for (int c=0;c<4;++c) async16(gA[c] + k0, lA0 + c*8*BK);
#pragma unroll
    for (int c=0;c<4;++c) async16(gB[c] + k0, lB0 + c*8*BK);
    __syncthreads();            // drains vmcnt: tiles staged (12 drains total)
#pragma unroll
    for (int ks=0;ks<2;++ks) {
      short8 af[4], bfr[4];
#pragma unroll
      for (int t=0;t<4;++t)
        af[t]  = *(const short8*)(sA + (wm + t*16 + l16)*BK + ((ks*4+quad) ^ (l16&7))*8);
#pragma unroll
      for (int t=0;t<4;++t)
        bfr[t] = *(const short8*)(sB + (wn + t*16 + l16)*BK + ((ks*4+quad) ^ (l16&7))*8);
#pragma unroll
      for (int mt=0;mt<4;++mt)
#pragma unroll
        for (int nt=0;nt<4;++nt)
          acc[mt][nt] = __builtin_amdgcn_mfma_f32_16x16x32_bf16(af[mt], bfr[nt], acc[mt][nt], 0,0,0);
    }
    __syncthreads();            // all reads done before next overwrite
  }

#pragma unroll
  for (int mt=0;mt<4;++mt)
#pragma unroll
    for (int nt=0;nt<4;++nt) {
      int col = n0 + wn + nt*16 + l16;
      if (col >= N) continue;
      float bia = bias[col];
      int rowb = m0 + wm + mt*16 + quad*4;
#pragma unroll
      for (int r=0;r<4;++r) {
        int row = rowb + r;
        if (row >= M) continue;
        float vacc = acc[mt][nt][r] + bia;
        size_t off = (size_t)row*N + col;
        if (EPI==0) {
          ((u16*)Cout)[off] = f2bf(vacc);
        } else if (EPI==1) {
          ((u16*)Cout)[off] = f2bf(((const float*)resid)[off] + vacc);
        } else {
          float gl = vacc / (1.f + __expf(-1.702f*vacc));
          ((float*)Cout)[off] = b2f(((const u16*)resid)[off]) + gl;
        }
      }
    }
}

// ---------------- Fused attention: per (n,h) pair x 64-row Q tile ----------------
// 1-D grid of 3840 with XCD-chunk swizzle: the 5 l0-sibling blocks of one (n,h)
// get consecutive work indices on the SAME XCD -> K/V re-reads hit that XCD's L2.
// Swizzle is bijective: linear = 8q+r -> wi = 480r+q, 3840 = 8 x 480.
__global__ __launch_bounds__(256,2) void attn_kernel(
    const u16* __restrict__ qkv, float* __restrict__ wout, u16* __restrict__ attn)
{
  __shared__ __align__(16) u16 smem[29696];  // 59392 B
  u16* sQ  = smem;               // [64][72]
  u16* sK  = smem + 64*72;       // [272][72]
  u16* sP  = smem;               // [64][296]
  u16* sVt = smem + 64*296;      // [64][168]
  const int linear = blockIdx.x;
  const int wi = (linear & 7)*480 + (linear >> 3);
  const int p = wi / 5;          // n*12 + h
  const int n = p / NHEAD, h = p % NHEAD;
  const int l0 = (wi % 5) * 64;
  const int tid = threadIdx.x, lane = tid & 63, w = tid >> 6;
  const int l16 = lane & 15, quad = lane >> 4;

  for (int i = tid; i < 64*8; i += 256) {
    int lr = i >> 3, c8 = (i & 7)*8;
    uint4 v = {0u,0u,0u,0u};
    int gl = l0 + lr;
    if (gl < LSEQ) v = *(const uint4*)(qkv + ((size_t)gl*NBATCH + n)*2304 + h*HDIM + c8);
    *(uint4*)(sQ + lr*72 + c8) = v;
  }
  for (int i = tid; i < 272*8; i += 256) {
    int kr = i >> 3, c8 = (i & 7)*8;
    uint4 v = {0u,0u,0u,0u};
    if (kr < LSEQ) v = *(const uint4*)(qkv + ((size_t)kr*NBATCH + n)*2304 + 768 + h*HDIM + c8);
    *(uint4*)(sK + kr*72 + c8) = v;
  }
  __syncthreads();

  floatx4 acc[17];
#pragma unroll
  for (int t=0;t<17;++t) acc[t] = (floatx4){0.f,0.f,0.f,0.f};
#pragma unroll
  for (int ks=0;ks<2;++ks) {
    short8 aq = *(const short8*)(sQ + (w*16 + l16)*72 + ks*32 + quad*8);
#pragma unroll
    for (int nt=0;nt<17;++nt) {
      short8 bk = *(const short8*)(sK + (nt*16 + l16)*72 + ks*32 + quad*8);
      acc[nt] = __builtin_amdgcn_mfma_f32_16x16x32_bf16(aq, bk, acc[nt], 0,0,0);
    }
  }
  __syncthreads();  // all sQ/sK reads complete before sP overwrites

#pragma unroll
  for (int r=0;r<4;++r) {
    float mx = -3.0e38f;
#pragma unroll
    for (int nt=0;nt<17;++nt) {
      int col = nt*16 + l16;
      float v = (col < LSEQ) ? acc[nt][r]*0.125f : -3.0e38f;
      acc[nt][r] = v;
      mx = fmaxf(mx, v);
    }
#pragma unroll
    for (int o=1;o<16;o<<=1) mx = fmaxf(mx, __shfl_xor(mx,o,64));
    float sum = 0.f;
#pragma unroll
    for (int nt=0;nt<17;++nt) {
      float e = __expf(acc[nt][r]-mx);
      acc[nt][r] = e; sum += e;
    }
#pragma unroll
    for (int o=1;o<16;o<<=1) sum += __shfl_xor(sum,o,64);
    float inv = 1.f/sum;
#pragma unroll
    for (int nt=0;nt<17;++nt) acc[nt][r] *= inv;
  }

  size_t wbase = (size_t)p * LSEQ * LSEQ;
#pragma unroll
  for (int r=0;r<4;++r) {
    int lr = w*16 + quad*4 + r;
    int gl = l0 + lr;
#pragma unroll
    for (int nt=0;nt<17;++nt) {
      int col = nt*16 + l16;
      sP[lr*296 + col] = f2bf(acc[nt][r]);
      if (gl < LSEQ && col < LSEQ) wout[wbase + (size_t)gl*LSEQ + col] = acc[nt][r];
    }
  }
  for (int i = tid; i < 64*16; i += 256) {
    int lr = i >> 4, c = 272 + (i & 15);
    sP[lr*296 + c] = 0;
  }
  __syncthreads();

  floatx4 acc2[4];
#pragma unroll
  for (int t=0;t<4;++t) acc2[t] = (floatx4){0.f,0.f,0.f,0.f};
  for (int c=0;c<2;++c) {
    if (c) __syncthreads();
    int mbase = c*160;
    int msz = c ? 128 : 160;
    for (int ml = tid; ml < msz; ml += 256) {
      int m = mbase + ml;
      if (m < LSEQ) {
        const u16* vr = qkv + ((size_t)m*NBATCH + n)*2304 + 1536 + h*HDIM;
#pragma unroll
        for (int d=0; d<64; ++d) sVt[d*168 + ml] = vr[d];
      } else {
#pragma unroll
        for (int d=0; d<64; ++d) sVt[d*168 + ml] = 0;
      }
    }
    __syncthreads();
    int nks = c ? 4 : 5;
    for (int ksl=0; ksl<nks; ++ksl) {
      short8 ap = *(const short8*)(sP + (w*16 + l16)*296 + mbase + ksl*32 + quad*8);
#pragma unroll
      for (int nt=0;nt<4;++nt) {
        short8 bv = *(const short8*)(sVt + (nt*16 + l16)*168 + ksl*32 + quad*8);
        acc2[nt] = __builtin_amdgcn_mfma_f32_16x16x32_bf16(ap, bv, acc2[nt], 0,0,0);
      }
    }
  }
#pragma unroll
  for (int nt=0;nt<4;++nt)
#pragma unroll
    for (int r=0;r<4;++r) {
      int lr = w*16 + quad*4 + r;
      int gl = l0 + lr;
      if (gl < LSEQ) {
        int d = nt*16 + l16;
        attn[((size_t)gl*NBATCH + n)*768 + h*HDIM + d] = f2bf(acc2[nt][r]);
      }
    }
}

extern "C" void kernel_launch(void* const* d_in, const int* in_sizes, int n_in,
                              void* d_out, int out_size, void* d_ws, size_t ws_size,
                              hipStream_t stream)
{
  (void)in_sizes; (void)n_in; (void)out_size; (void)ws_size;
  const float* x    = (const float*)d_in[0];
  const float* w_in = (const float*)d_in[1];
  const float* b_in = (const float*)d_in[2];
  const float* w_op = (const float*)d_in[3];
  const float* b_op = (const float*)d_in[4];
  const float* g1   = (const float*)d_in[5];
  const float* b1   = (const float*)d_in[6];
  const float* g2   = (const float*)d_in[7];
  const float* b2v  = (const float*)d_in[8];
  const float* wfc  = (const float*)d_in[9];
  const float* bfc  = (const float*)d_in[10];

  float* out_x = (float*)d_out;
  float* out_w = out_x + (size_t)MROWS*D_MODEL;

  char* ws = (char*)d_ws;
  u16* qkv  = (u16*)ws;                                                 // 75.79 MB
  u16* hbuf = (u16*)(ws + (size_t)MROWS*2304*2);                        // h then attn, 25.26 MB
  u16* x2b  = (u16*)(ws + (size_t)MROWS*2304*2 + (size_t)MROWS*768*2);  // x2 bf16, 25.26 MB

  // Overlaid bf16 weight buffers (no extra workspace):
  //  - w_in_bf in x2b region (x2b first written at out_proj, after QKV GEMM consumed w_in_bf)
  //  - w_op_bf/w_fc_bf at qkv+48MB (qkv dead after attn; LN2 writes only first 25.26MB)
  u16* w_in_bf = x2b;
  u16* w_op_bf = qkv + (size_t)24*1024*1024;
  u16* w_fc_bf = w_op_bf + 768*768;

  dim3 blk(256);
  // convert in_proj weights fp32->bf16 (2304*768/8 = 221184 vec8)
  cvt_bf16<<<dim3(864), blk, 0, stream>>>(w_in, w_in_bf, 221184);
  // LN1: x (fp32) -> h (bf16)
  ln_kernel<float><<<dim3(MROWS/4), blk, 0, stream>>>(x, g1, b1, hbuf, MROWS);
  // QKV: h @ in_proj_w^T + b   (grid: x=N-blocks for A-tile reuse)
  gemm_bt<0><<<dim3(18,129), blk, 0, stream>>>(hbuf, w_in_bf, b_in, qkv, nullptr, MROWS, 2304, 768);
  // attention: qkv -> weights (d_out tail, fp32) + attn (hbuf, bf16); XCD-swizzled 1-D grid
  attn_kernel<<<dim3(3840), blk, 0, stream>>>(qkv, out_w, hbuf);
  // convert out_proj / fc weights (qkv now dead)
  cvt_bf16<<<dim3(288), blk, 0, stream>>>(w_op, w_op_bf, 73728);
  cvt_bf16<<<dim3(288), blk, 0, stream>>>(wfc,  w_fc_bf, 73728);
  // out_proj + residual(x fp32) -> x2 (bf16)
  gemm_bt<1><<<dim3(6,129), blk, 0, stream>>>(hbuf, w_op_bf, b_op, x2b, x, MROWS, 768, 768);
  // LN2: x2 (bf16) -> h2 (bf16, reuse qkv buffer head)
  ln_kernel<u16><<<dim3(MROWS/4), blk, 0, stream>>>(x2b, g2, b2v, qkv, MROWS);
  // fc + quickgelu + residual(x2 bf16) -> out_x (fp32)
  gemm_bt<2><<<dim3(6,129), blk, 0, stream>>>(qkv, w_fc_bf, bfc, out_x, x2b, MROWS, 768, 768);
}